// Round 3
// baseline (503.896 us; speedup 1.0000x reference)
//
#include <hip/hip_runtime.h>
#include <hip/hip_bf16.h>
#include <hip/hip_fp16.h>

// Problem constants (match reference)
#define N_NODES 100000
#define N_EDGES 1600000
#define N_GRAPHS 128

// Counting-sort CSR build parameters
#define BSH 9                 // bucket = col >> 9
#define BNODES 512            // nodes per bucket
#define NB 196                // ceil(100000 / 512)
#define CAP 18432             // static per-bucket csr/record capacity (elems, x16-pad worst case)
#define BLK 512               // histogram blocks
#define EPB (N_EDGES / BLK)   // 3125 edges per block (exact)
#define RECMAX 10240          // max records per bucket held in LDS

#define SPLIT 4               // pooling blocks per graph

// Channel-sliced gather table: 4 slices x 16 ch, each slice 3.2 MB (< 4 MB
// per-XCD L2). SLS = slice stride in rows (+8 rows: one zero sentinel @ N_NODES).
#define NSLICE 4
#define SLS (N_NODES + 8)

typedef __attribute__((ext_vector_type(8))) _Float16 v8h;
typedef __attribute__((ext_vector_type(4))) float v4f;
typedef __attribute__((ext_vector_type(4))) int vi4;    // native vecs for nontemporal builtins
typedef __attribute__((ext_vector_type(2))) int vi2;
typedef __attribute__((ext_vector_type(4))) float vf4;

// unpack 2 halves packed in an int -> float2 (value-level, no vector-elem address)
__device__ __forceinline__ float2 h2f(int bits) {
    return __half22float2(__builtin_bit_cast(__half2, bits));
}

// ---------------- CSR build (no global atomics) ----------------

__global__ __launch_bounds__(256) void k_hist(const int* __restrict__ col,
                                              int* __restrict__ hist_t) {
    __shared__ int h[NB];
    const int t = threadIdx.x, b = blockIdx.x;
    for (int i = t; i < NB; i += 256) h[i] = 0;
    __syncthreads();
    const int e0 = b * EPB;
    for (int i = t; i < EPB; i += 256) atomicAdd(&h[col[e0 + i] >> BSH], 1);
    __syncthreads();
    for (int i = t; i < NB; i += 256) hist_t[i * BLK + b] = h[i];
}

__global__ __launch_bounds__(512) void k_cursors(const int* __restrict__ hist_t,
                                                 int* __restrict__ cursors,
                                                 int* __restrict__ bcnt) {
    __shared__ int s[BLK];
    const int t = threadIdx.x, bin = blockIdx.x;
    const int v = hist_t[bin * BLK + t];
    s[t] = v; __syncthreads();
    for (int off = 1; off < BLK; off <<= 1) {
        int a = (t >= off) ? s[t - off] : 0;
        __syncthreads(); s[t] += a; __syncthreads();
    }
    cursors[bin * BLK + t] = bin * CAP + s[t] - v;   // exclusive + static base
    if (t == BLK - 1) bcnt[bin] = s[t];
}

__global__ __launch_bounds__(256) void k_mid(const int* __restrict__ row,
                                             const int* __restrict__ col,
                                             const int* __restrict__ cursors,
                                             int* __restrict__ bedges) {
    __shared__ int cur[NB];
    const int t = threadIdx.x, b = blockIdx.x;
    for (int i = t; i < NB; i += 256) cur[i] = cursors[i * BLK + b];
    __syncthreads();
    const int e0 = b * EPB;
    for (int i = t; i < EPB; i += 256) {
        const int c = col[e0 + i];
        const int r = row[e0 + i];
        const int pos = atomicAdd(&cur[c >> BSH], 1);
        bedges[pos] = r | ((c & (BNODES - 1)) << 17);   // row<2^17, lcol 9 bits
    }
}

__global__ __launch_bounds__(512) void k_build(const int* __restrict__ bedges,
                                               const int* __restrict__ bcnt,
                                               int* __restrict__ csr,
                                               int* __restrict__ offs,
                                               int* __restrict__ deg_c,
                                               float* __restrict__ dinv) {
    __shared__ int rec[RECMAX];
    __shared__ int deg[BNODES];
    __shared__ int offx[BNODES];
    __shared__ int cur[BNODES];
    const int t = threadIdx.x, bin = blockIdx.x;
    const int base = bin * CAP;
    const int cnt = bcnt[bin];
    const int vb = bin << BSH;
    const int nn = min(BNODES, N_NODES - vb);
    for (int i = t; i < cnt; i += 512) rec[i] = bedges[base + i];
    deg[t] = 0;
    __syncthreads();                 // all record loads done before any csr write
    for (int i = t; i < cnt; i += 512) atomicAdd(&deg[(rec[i] >> 17) & (BNODES - 1)], 1);
    __syncthreads();
    const int d = (t < nn) ? deg[t] : 0;
    const int pd = (d + 15) & ~15;   // pad each segment to x16 (int4 edge loads in k_prop)
    offx[t] = pd; __syncthreads();
    for (int off = 1; off < BNODES; off <<= 1) {
        int a = (t >= off) ? offx[t - off] : 0;
        __syncthreads(); offx[t] += a; __syncthreads();
    }
    const int myoff = offx[t] - pd;  // exclusive
    cur[t] = myoff;
    if (t < nn) {
        offs[vb + t] = base + myoff;
        deg_c[vb + t] = d;
        dinv[vb + t] = (d > 0) ? rsqrtf((float)d) : 0.0f;
        for (int j = d; j < pd; j++) csr[base + myoff + j] = N_NODES;  // sentinel
    }
    __syncthreads();
    for (int i = t; i < cnt; i += 512) {
        const int r = rec[i];
        const int pos = atomicAdd(&cur[(r >> 17) & (BNODES - 1)], 1);
        csr[base + pos] = r & 0x1FFFF;
    }
}

// ---------------- MFMA GEMM: H16[slice][n][16] = fp16(dinv[n] * (X[n,:] @ W)) ----------
// 128-node x 64-ch block tile, 4 waves. fp16 inputs, fp32 accumulate; W split
// hi+lo fp16 so weight rounding is ~exact. TIN = float (layer 1, row-major x) or
// __half (layers 2-4, slice-major [slice][node][16] with stride N_NODES).
// Output H16 is slice-major with stride SLS (gather table).

template <int CIN, typename TIN>
__global__ __launch_bounds__(256) void k_gemm(const TIN* __restrict__ X,
                                              const float* __restrict__ W,
                                              const float* __restrict__ dinv,
                                              __half* __restrict__ H16) {
    constexpr int SA = 72;                       // halves per node row (pad 8)
    constexpr int SB = 72;
    __shared__ __align__(16) _Float16 sA[128 * SA];   // 18.4 KB
    __shared__ __align__(16) _Float16 sBh[64 * SB];   // 9.2 KB
    __shared__ __align__(16) _Float16 sBl[64 * SB];   // 9.2 KB
    const int t = threadIdx.x;
    const int w = t >> 6, lane = t & 63;
    const int quad = lane >> 4, l16 = lane & 15;
    const int nb = blockIdx.x * 128;

    v4f acc[2][4] = {};   // [mtile][ntile]

    for (int k0 = 0; k0 < CIN; k0 += 64) {
        if (k0) __syncthreads();
        // stage W chunk [64k x 64c] -> transposed hi/lo [c][k]
        for (int i = t; i < 64 * 16; i += 256) {
            const int k = i >> 4, c4 = (i & 15) * 4;
            const float4 wv = *reinterpret_cast<const float4*>(W + (size_t)(k0 + k) * 64 + c4);
            const float wf[4] = {wv.x, wv.y, wv.z, wv.w};
            #pragma unroll
            for (int j = 0; j < 4; j++) {
                const _Float16 hi = (_Float16)wf[j];
                sBh[(c4 + j) * SB + k] = hi;
                sBl[(c4 + j) * SB + k] = (_Float16)(wf[j] - (float)hi);
            }
        }
        // stage X chunk [128 nodes x 64k]
        if constexpr (sizeof(TIN) == 4) {         // fp32 row-major -> fp16 convert
            for (int i = t; i < 128 * 16; i += 256) {
                const int node = i >> 4, k4 = (i & 15) * 4;
                const int gn = nb + node;
                float4 v = make_float4(0.f, 0.f, 0.f, 0.f);
                if (gn < N_NODES)
                    v = *reinterpret_cast<const float4*>((const float*)X + (size_t)gn * CIN + k0 + k4);
                _Float16* d = &sA[node * SA + k4];
                d[0] = (_Float16)v.x; d[1] = (_Float16)v.y;
                d[2] = (_Float16)v.z; d[3] = (_Float16)v.w;
            }
        } else {                                   // fp16 slice-major raw copy (CIN==64, k0==0)
            for (int i = t; i < 128 * 8; i += 256) {
                const int off8 = (i & 1) * 8;      // 0 or 8 halves within slice
                const int node = (i >> 1) & 127;
                const int sl = i >> 8;             // channel slice 0..3
                const int gn = nb + node;
                int4 v = make_int4(0, 0, 0, 0);
                if (gn < N_NODES)
                    v = *reinterpret_cast<const int4*>(
                        (const __half*)X + ((size_t)sl * N_NODES + gn) * 16 + off8);
                *reinterpret_cast<int4*>(&sA[node * SA + sl * 16 + off8]) = v;
            }
        }
        __syncthreads();

        #pragma unroll
        for (int kt = 0; kt < 2; kt++) {
            const int kb = kt * 32 + quad * 8;
            v8h afr[2], bh[4], bl[4];
            #pragma unroll
            for (int mt = 0; mt < 2; mt++)
                afr[mt] = *reinterpret_cast<const v8h*>(&sA[(w * 32 + mt * 16 + l16) * SA + kb]);
            #pragma unroll
            for (int nt = 0; nt < 4; nt++) {
                bh[nt] = *reinterpret_cast<const v8h*>(&sBh[(nt * 16 + l16) * SB + kb]);
                bl[nt] = *reinterpret_cast<const v8h*>(&sBl[(nt * 16 + l16) * SB + kb]);
            }
            #pragma unroll
            for (int mt = 0; mt < 2; mt++)
                #pragma unroll
                for (int nt = 0; nt < 4; nt++) {
                    acc[mt][nt] = __builtin_amdgcn_mfma_f32_16x16x32_f16(afr[mt], bh[nt], acc[mt][nt], 0, 0, 0);
                    acc[mt][nt] = __builtin_amdgcn_mfma_f32_16x16x32_f16(afr[mt], bl[nt], acc[mt][nt], 0, 0, 0);
                }
        }
    }

    // epilogue: D row = quad*4+reg, col = l16; nt is the channel slice
    #pragma unroll
    for (int mt = 0; mt < 2; mt++) {
        #pragma unroll
        for (int reg = 0; reg < 4; reg++) {
            const int node = nb + w * 32 + mt * 16 + quad * 4 + reg;
            if (node < N_NODES) {
                const float dv = dinv[node];
                #pragma unroll
                for (int nt = 0; nt < 4; nt++)
                    H16[((size_t)nt * SLS + node) * 16 + l16] =
                        __float2half(acc[mt][nt][reg] * dv);
            }
        }
    }
}

// ---------------- propagation (channel-sliced): ----------------
// Hout[s][v][16] = dinv[v] * sum_e fp32(H16[s][row_e][16]) + bias[s*16..]
// gridDim = (N_NODES/16, NSLICE); blockIdx.y = slice. All slice-0 blocks
// dispatch before slice-1 -> each XCD's L2 holds the 3.2 MB slice table.
// Wave = 4 nodes (quads); within a quad: 4 edge-slots x 4 ch-groups.
// Each lane: one int4 of edge ids (NT load, don't pollute L2) + 4 8-B
// gathers per 16-edge step. Cross-slot reduce via 2 shfl_xor.
// TOUT = __half (layers 1-3, slice-major stride N_NODES) or float (layer 4).

template <typename TOUT>
__global__ __launch_bounds__(256) void k_prop(const __half* __restrict__ Hin,
                                              const int* __restrict__ csr,
                                              const int* __restrict__ offs,
                                              const int* __restrict__ deg_c,
                                              const float* __restrict__ dinv,
                                              const float* __restrict__ bias,
                                              TOUT* __restrict__ Hout) {
    const int wave = threadIdx.x >> 6, lane = threadIdx.x & 63;
    const int quad = lane >> 4;            // node slot within the wave
    const int es = (lane >> 2) & 3;        // edge slot (4 edges in parallel)
    const int cg = lane & 3;               // channel group: 4 ch, 8 B
    const int s = blockIdx.y;              // channel slice
    const int v = blockIdx.x * 16 + wave * 4 + quad;   // grid exact: v < N_NODES
    const int start = offs[v];             // multiple of 16 -> int4-aligned
    const int cp = (deg_c[v] + 15) & ~15;
    const int* ep = csr + start + es * 4;
    const __half* hb = Hin + (size_t)s * SLS * 16 + cg * 4;
    float a0 = 0.f, a1 = 0.f, a2 = 0.f, a3 = 0.f;
    for (int j = 0; j < cp; j += 16) {     // per-quad trip count (exec mask)
        const vi4 e = __builtin_nontemporal_load(reinterpret_cast<const vi4*>(ep + j));
        const vi2 r0 = *reinterpret_cast<const vi2*>(hb + (size_t)e.x * 16);
        const vi2 r1 = *reinterpret_cast<const vi2*>(hb + (size_t)e.y * 16);
        const vi2 r2 = *reinterpret_cast<const vi2*>(hb + (size_t)e.z * 16);
        const vi2 r3 = *reinterpret_cast<const vi2*>(hb + (size_t)e.w * 16);
        #define ACC(r) { \
            const float2 u = h2f(r.x); \
            const float2 w = h2f(r.y); \
            a0 += u.x; a1 += u.y; a2 += w.x; a3 += w.y; }
        ACC(r0) ACC(r1) ACC(r2) ACC(r3)
        #undef ACC
    }
    // reduce across the 4 edge-slots (lanes l, l^4, l^8 within the quad)
    a0 += __shfl_xor(a0, 4); a1 += __shfl_xor(a1, 4);
    a2 += __shfl_xor(a2, 4); a3 += __shfl_xor(a3, 4);
    a0 += __shfl_xor(a0, 8); a1 += __shfl_xor(a1, 8);
    a2 += __shfl_xor(a2, 8); a3 += __shfl_xor(a3, 8);
    if (es == 0) {
        const float dv = dinv[v];
        const float4 bs = *reinterpret_cast<const float4*>(bias + s * 16 + cg * 4);
        const float o0 = dv * a0 + bs.x, o1 = dv * a1 + bs.y;
        const float o2 = dv * a2 + bs.z, o3 = dv * a3 + bs.w;
        if constexpr (sizeof(TOUT) == 2) {
            vi2 pk;
            pk.x = __builtin_bit_cast(int, __floats2half2_rn(o0, o1));
            pk.y = __builtin_bit_cast(int, __floats2half2_rn(o2, o3));
            __builtin_nontemporal_store(pk,
                reinterpret_cast<vi2*>((__half*)Hout + ((size_t)s * N_NODES + v) * 16 + cg * 4));
        } else {
            vf4 o; o.x = o0; o.y = o1; o.z = o2; o.w = o3;
            __builtin_nontemporal_store(o,
                reinterpret_cast<vf4*>((float*)Hout + ((size_t)s * N_NODES + v) * 16 + cg * 4));
        }
    }
}

// ---------------- pooling: one (graph, split) block; atomic-free partials ----------------
// H is slice-major fp32 [slice][node][16]; lane -> (slice = lane>>4, ch = lane&15)
// so global channel == lane and the partial layout is unchanged.

__global__ __launch_bounds__(256) void k_pool(const float* __restrict__ H,
                                              const int* __restrict__ batch,
                                              float* __restrict__ partial) {
    const int g = blockIdx.x >> 2;           // graph
    const int s = blockIdx.x & (SPLIT - 1);  // split
    int lo = 0, hi = N_NODES;
    while (lo < hi) { int m = (lo + hi) >> 1; if (batch[m] < g) lo = m + 1; else hi = m; }
    const int a = lo;
    lo = 0; hi = N_NODES;
    while (lo < hi) { int m = (lo + hi) >> 1; if (batch[m] < g + 1) lo = m + 1; else hi = m; }
    const int b = lo;

    const int wave = threadIdx.x >> 6, lane = threadIdx.x & 63;
    const int lane16 = s * 4 + wave;         // 0..15: stride position
    const size_t sbase = (size_t)(lane >> 4) * ((size_t)N_NODES * 16) + (lane & 15);
    float ac0 = 0.f, ac1 = 0.f, ac2 = 0.f, ac3 = 0.f;
    int v = a + lane16;
    for (; v + 48 < b; v += 64) {            // 4 independent loads in flight
        ac0 += H[sbase + (size_t)v * 16];
        ac1 += H[sbase + (size_t)(v + 16) * 16];
        ac2 += H[sbase + (size_t)(v + 32) * 16];
        ac3 += H[sbase + (size_t)(v + 48) * 16];
    }
    for (; v < b; v += 16) ac0 += H[sbase + (size_t)v * 16];
    const float acc = (ac0 + ac1) + (ac2 + ac3);

    __shared__ float red[4][64];
    red[wave][lane] = acc;
    __syncthreads();
    if (wave == 0) {
        const float r = (red[0][lane] + red[1][lane]) + (red[2][lane] + red[3][lane]);
        partial[((size_t)s * N_GRAPHS + g) * 64 + lane] = r;
    }
}

__global__ void k_final(const float* __restrict__ partial, const int* __restrict__ batch,
                        const float* __restrict__ Wl, const float* __restrict__ bl,
                        float* __restrict__ out) {
    __shared__ int scnt[128];
    int t = threadIdx.x;
    int lo = 0, hi = N_NODES;
    while (lo < hi) { int mid = (lo + hi) >> 1; if (batch[mid] < t) lo = mid + 1; else hi = mid; }
    int a = lo;
    lo = 0; hi = N_NODES;
    while (lo < hi) { int mid = (lo + hi) >> 1; if (batch[mid] < t + 1) lo = mid + 1; else hi = mid; }
    scnt[t] = lo - a;
    __syncthreads();
    for (int off = 64; off > 0; off >>= 1) {
        if (t < off) scnt[t] = max(scnt[t], scnt[t + off]);
        __syncthreads();
    }
    const float nmax = (float)scnt[0];
    float s = 0.f;
    for (int c = 0; c < 64; c++) {
        float g = 0.f;
        #pragma unroll
        for (int p = 0; p < SPLIT; p++)
            g += partial[((size_t)p * N_GRAPHS + t) * 64 + c];
        s += g * Wl[c];
    }
    out[t] = s / nmax + bl[0];
}

// ---------------- launch ----------------

extern "C" void kernel_launch(void* const* d_in, const int* in_sizes, int n_in,
                              void* d_out, int out_size, void* d_ws, size_t ws_size,
                              hipStream_t stream) {
    const float* x    = (const float*)d_in[0];
    const int*   ei   = (const int*)d_in[1];     // [2, E] int32
    const int*   batch= (const int*)d_in[2];
    const float* W1 = (const float*)d_in[3];  const float* b1 = (const float*)d_in[4];
    const float* W2 = (const float*)d_in[5];  const float* b2 = (const float*)d_in[6];
    const float* W3 = (const float*)d_in[7];  const float* b3 = (const float*)d_in[8];
    const float* W4 = (const float*)d_in[9];  const float* b4 = (const float*)d_in[10];
    const float* Wl = (const float*)d_in[11]; const float* bl = (const float*)d_in[12];
    float* out = (float*)d_out;

    const int* row = ei;
    const int* col = ei + N_EDGES;

    // workspace layout (256B aligned blocks)
    char* ws = (char*)d_ws;
    size_t off = 0;
    auto alloc = [&](size_t bytes) {
        void* p = ws + off;
        off = (off + bytes + 255) & ~(size_t)255;
        return p;
    };
    int*    hist_t  = (int*)alloc((size_t)NB * BLK * 4);
    int*    cursors = (int*)alloc((size_t)NB * BLK * 4);
    int*    bcnt    = (int*)alloc(NB * 4);
    int*    bedges  = (int*)alloc((size_t)NB * CAP * 4);   // aliased by csr
    int*    csr     = bedges;                              // in-place rebuild (safe)
    int*    offs    = (int*)alloc(N_NODES * 4);
    int*    deg_c   = (int*)alloc(N_NODES * 4);
    float*  dinv    = (float*)alloc(N_NODES * 4);
    __half* h16     = (__half*)alloc((size_t)NSLICE * SLS * 16 * 2);   // sliced gather table
    __half* h_c     = (__half*)alloc((size_t)NSLICE * N_NODES * 16 * 2); // fp16 prop out (L1-3)
    float*  h_b     = (float*)alloc((size_t)NSLICE * N_NODES * 16 * 4);  // fp32 prop out (L4)
    float*  partial = (float*)alloc((size_t)SPLIT * N_GRAPHS * 64 * 4);

    // zero the per-slice sentinel rows (row N_NODES of each slice, 32 B each)
    for (int s = 0; s < NSLICE; ++s)
        (void)hipMemsetAsync(h16 + ((size_t)s * SLS + N_NODES) * 16, 0, 16 * 2, stream);

    // CSR build: histogram -> cursors -> bucket scatter -> per-bucket build
    k_hist<<<BLK, 256, 0, stream>>>(col, hist_t);
    k_cursors<<<NB, 512, 0, stream>>>(hist_t, cursors, bcnt);
    k_mid<<<BLK, 256, 0, stream>>>(row, col, cursors, bedges);
    k_build<<<NB, 512, 0, stream>>>(bedges, bcnt, csr, offs, deg_c, dinv);

    const int GB = (N_NODES + 127) / 128;   // 782 gemm blocks
    const dim3 gprop(N_NODES / 16, NSLICE); // 6250 x 4: slice-phase ordering

    // layer 1: h16 = fp16(dinv * (x @ W1)) ; h_c = fp16(dinv * prop(h16) + b1)
    k_gemm<128, float><<<GB, 256, 0, stream>>>(x, W1, dinv, h16);
    k_prop<__half><<<gprop, 256, 0, stream>>>(h16, csr, offs, deg_c, dinv, b1, h_c);
    // layer 2
    k_gemm<64, __half><<<GB, 256, 0, stream>>>(h_c, W2, dinv, h16);
    k_prop<__half><<<gprop, 256, 0, stream>>>(h16, csr, offs, deg_c, dinv, b2, h_c);
    // layer 3
    k_gemm<64, __half><<<GB, 256, 0, stream>>>(h_c, W3, dinv, h16);
    k_prop<__half><<<gprop, 256, 0, stream>>>(h16, csr, offs, deg_c, dinv, b3, h_c);
    // layer 4: fp32 output for pooling
    k_gemm<64, __half><<<GB, 256, 0, stream>>>(h_c, W4, dinv, h16);
    k_prop<float><<<gprop, 256, 0, stream>>>(h16, csr, offs, deg_c, dinv, b4, h_b);

    // pooling + readout (atomic-free)
    k_pool<<<N_GRAPHS * SPLIT, 256, 0, stream>>>(h_b, batch, partial);
    k_final<<<1, 128, 0, stream>>>(partial, batch, Wl, bl, out);
}

// Round 4
// 393.653 us; speedup vs baseline: 1.2801x; 1.2801x over previous
//
#include <hip/hip_runtime.h>
#include <hip/hip_bf16.h>
#include <hip/hip_fp16.h>

// Problem constants (match reference)
#define N_NODES 100000
#define N_EDGES 1600000
#define N_GRAPHS 128

// Counting-sort CSR build parameters (baseline: pad-8)
#define BSH 9                 // bucket = col >> 9
#define BNODES 512            // nodes per bucket
#define NB 196                // ceil(100000 / 512)
#define CAP 12288             // static per-bucket csr/record capacity (elems)
#define BLK 512               // histogram blocks
#define EPB (N_EDGES / BLK)   // 3125 edges per block (exact)
#define RECMAX 10240          // max records per bucket held in LDS

#define SPLIT 4               // pooling blocks per graph

typedef __attribute__((ext_vector_type(8))) _Float16 v8h;
typedef __attribute__((ext_vector_type(4))) float v4f;
typedef __attribute__((ext_vector_type(4))) int vi4;    // native vecs for nontemporal builtins
typedef __attribute__((ext_vector_type(2))) int vi2;
typedef __attribute__((ext_vector_type(4))) float vf4;

// unpack 2 halves packed in an int -> float2 (value-level)
__device__ __forceinline__ float2 h2f(int bits) {
    return __half22float2(__builtin_bit_cast(__half2, bits));
}

// ---------------- CSR build (no global atomics) ----------------

__global__ __launch_bounds__(256) void k_hist(const int* __restrict__ col,
                                              int* __restrict__ hist_t) {
    __shared__ int h[NB];
    const int t = threadIdx.x, b = blockIdx.x;
    for (int i = t; i < NB; i += 256) h[i] = 0;
    __syncthreads();
    const int e0 = b * EPB;
    for (int i = t; i < EPB; i += 256) atomicAdd(&h[col[e0 + i] >> BSH], 1);
    __syncthreads();
    for (int i = t; i < NB; i += 256) hist_t[i * BLK + b] = h[i];
}

__global__ __launch_bounds__(512) void k_cursors(const int* __restrict__ hist_t,
                                                 int* __restrict__ cursors,
                                                 int* __restrict__ bcnt) {
    __shared__ int s[BLK];
    const int t = threadIdx.x, bin = blockIdx.x;
    const int v = hist_t[bin * BLK + t];
    s[t] = v; __syncthreads();
    for (int off = 1; off < BLK; off <<= 1) {
        int a = (t >= off) ? s[t - off] : 0;
        __syncthreads(); s[t] += a; __syncthreads();
    }
    cursors[bin * BLK + t] = bin * CAP + s[t] - v;   // exclusive + static base
    if (t == BLK - 1) bcnt[bin] = s[t];
}

__global__ __launch_bounds__(256) void k_mid(const int* __restrict__ row,
                                             const int* __restrict__ col,
                                             const int* __restrict__ cursors,
                                             int* __restrict__ bedges) {
    __shared__ int cur[NB];
    const int t = threadIdx.x, b = blockIdx.x;
    for (int i = t; i < NB; i += 256) cur[i] = cursors[i * BLK + b];
    __syncthreads();
    const int e0 = b * EPB;
    for (int i = t; i < EPB; i += 256) {
        const int c = col[e0 + i];
        const int r = row[e0 + i];
        const int pos = atomicAdd(&cur[c >> BSH], 1);
        bedges[pos] = r | ((c & (BNODES - 1)) << 17);   // row<2^17, lcol 9 bits
    }
}

__global__ __launch_bounds__(512) void k_build(const int* __restrict__ bedges,
                                               const int* __restrict__ bcnt,
                                               int* __restrict__ csr,
                                               int* __restrict__ offs,
                                               int* __restrict__ deg_c,
                                               float* __restrict__ dinv) {
    __shared__ int rec[RECMAX];
    __shared__ int deg[BNODES];
    __shared__ int offx[BNODES];
    __shared__ int cur[BNODES];
    const int t = threadIdx.x, bin = blockIdx.x;
    const int base = bin * CAP;
    const int cnt = bcnt[bin];
    const int vb = bin << BSH;
    const int nn = min(BNODES, N_NODES - vb);
    for (int i = t; i < cnt; i += 512) rec[i] = bedges[base + i];
    deg[t] = 0;
    __syncthreads();                 // all record loads done before any csr write
    for (int i = t; i < cnt; i += 512) atomicAdd(&deg[(rec[i] >> 17) & (BNODES - 1)], 1);
    __syncthreads();
    const int d = (t < nn) ? deg[t] : 0;
    const int pd = (d + 7) & ~7;     // pad each segment to x8 (8-deep gather unroll)
    offx[t] = pd; __syncthreads();
    for (int off = 1; off < BNODES; off <<= 1) {
        int a = (t >= off) ? offx[t - off] : 0;
        __syncthreads(); offx[t] += a; __syncthreads();
    }
    const int myoff = offx[t] - pd;  // exclusive
    cur[t] = myoff;
    if (t < nn) {
        offs[vb + t] = base + myoff;
        deg_c[vb + t] = d;
        dinv[vb + t] = (d > 0) ? rsqrtf((float)d) : 0.0f;
        for (int j = d; j < pd; j++) csr[base + myoff + j] = N_NODES;  // sentinel
    }
    __syncthreads();
    for (int i = t; i < cnt; i += 512) {
        const int r = rec[i];
        const int pos = atomicAdd(&cur[(r >> 17) & (BNODES - 1)], 1);
        csr[base + pos] = r & 0x1FFFF;
    }
}

// ---------------- MFMA GEMM (layer 1 only): H16[n][64] = fp16(dinv[n]*(X[n,:]@W)) ----
// 128-node x 64-ch block tile, 4 waves. fp32 input, fp16 staging, fp32 accum;
// W split hi+lo fp16 so weight rounding is ~exact.

template <int CIN>
__global__ __launch_bounds__(256) void k_gemm(const float* __restrict__ X,
                                              const float* __restrict__ W,
                                              const float* __restrict__ dinv,
                                              __half* __restrict__ H16) {
    constexpr int SA = 72;                       // halves per node row (pad 8)
    constexpr int SB = 72;
    __shared__ __align__(16) _Float16 sA[128 * SA];   // 18.4 KB
    __shared__ __align__(16) _Float16 sBh[64 * SB];   // 9.2 KB
    __shared__ __align__(16) _Float16 sBl[64 * SB];   // 9.2 KB
    const int t = threadIdx.x;
    const int w = t >> 6, lane = t & 63;
    const int quad = lane >> 4, l16 = lane & 15;
    const int nb = blockIdx.x * 128;

    v4f acc[2][4] = {};   // [mtile][ntile]

    for (int k0 = 0; k0 < CIN; k0 += 64) {
        if (k0) __syncthreads();
        // stage W chunk [64k x 64c] -> transposed hi/lo [c][k]
        for (int i = t; i < 64 * 16; i += 256) {
            const int k = i >> 4, c4 = (i & 15) * 4;
            const float4 wv = *reinterpret_cast<const float4*>(W + (size_t)(k0 + k) * 64 + c4);
            const float wf[4] = {wv.x, wv.y, wv.z, wv.w};
            #pragma unroll
            for (int j = 0; j < 4; j++) {
                const _Float16 hi = (_Float16)wf[j];
                sBh[(c4 + j) * SB + k] = hi;
                sBl[(c4 + j) * SB + k] = (_Float16)(wf[j] - (float)hi);
            }
        }
        // stage X chunk [128 nodes x 64k] (fp32 -> fp16)
        for (int i = t; i < 128 * 16; i += 256) {
            const int node = i >> 4, k4 = (i & 15) * 4;
            const int gn = nb + node;
            float4 v = make_float4(0.f, 0.f, 0.f, 0.f);
            if (gn < N_NODES)
                v = *reinterpret_cast<const float4*>(X + (size_t)gn * CIN + k0 + k4);
            _Float16* d = &sA[node * SA + k4];
            d[0] = (_Float16)v.x; d[1] = (_Float16)v.y;
            d[2] = (_Float16)v.z; d[3] = (_Float16)v.w;
        }
        __syncthreads();

        #pragma unroll
        for (int kt = 0; kt < 2; kt++) {
            const int kb = kt * 32 + quad * 8;
            v8h afr[2], bh[4], bl[4];
            #pragma unroll
            for (int mt = 0; mt < 2; mt++)
                afr[mt] = *reinterpret_cast<const v8h*>(&sA[(w * 32 + mt * 16 + l16) * SA + kb]);
            #pragma unroll
            for (int nt = 0; nt < 4; nt++) {
                bh[nt] = *reinterpret_cast<const v8h*>(&sBh[(nt * 16 + l16) * SB + kb]);
                bl[nt] = *reinterpret_cast<const v8h*>(&sBl[(nt * 16 + l16) * SB + kb]);
            }
            #pragma unroll
            for (int mt = 0; mt < 2; mt++)
                #pragma unroll
                for (int nt = 0; nt < 4; nt++) {
                    acc[mt][nt] = __builtin_amdgcn_mfma_f32_16x16x32_f16(afr[mt], bh[nt], acc[mt][nt], 0, 0, 0);
                    acc[mt][nt] = __builtin_amdgcn_mfma_f32_16x16x32_f16(afr[mt], bl[nt], acc[mt][nt], 0, 0, 0);
                }
        }
    }

    // epilogue: D row = quad*4+reg, col = l16
    #pragma unroll
    for (int mt = 0; mt < 2; mt++) {
        #pragma unroll
        for (int reg = 0; reg < 4; reg++) {
            const int node = nb + w * 32 + mt * 16 + quad * 4 + reg;
            if (node < N_NODES) {
                const float dv = dinv[node];
                #pragma unroll
                for (int nt = 0; nt < 4; nt++)
                    H16[(size_t)node * 64 + nt * 16 + l16] =
                        __float2half(acc[mt][nt][reg] * dv);
            }
        }
    }
}

// ---------------- standalone propagation (layer 4): fp32 out for pooling ----------
// Baseline structure: 4 nodes/wave (quads), lane owns 4 channels (8 B); each
// gather inst serves 4 full 128B rows (8 lanes per 64B line); 8-deep unroll.

__global__ __launch_bounds__(256) void k_prop_f(const __half* __restrict__ Hin,
                                                const int* __restrict__ csr,
                                                const int* __restrict__ offs,
                                                const int* __restrict__ deg_c,
                                                const float* __restrict__ dinv,
                                                const float* __restrict__ bias,
                                                float* __restrict__ Hout) {
    const int wave = threadIdx.x >> 6, lane = threadIdx.x & 63;
    const int quad = lane >> 4;            // node slot within the wave
    const int l = lane & 15;               // channel group: channels 4l..4l+3
    const int v = blockIdx.x * 16 + wave * 4 + quad;   // grid exact: v < N_NODES
    const int start = offs[v];             // multiple of 8 -> 32B aligned
    const int cp = (deg_c[v] + 7) & ~7;
    const int* ep = csr + start;
    const __half* hb = Hin + l * 4;
    float a0 = 0.f, a1 = 0.f, a2 = 0.f, a3 = 0.f;
    for (int j = 0; j < cp; j += 8) {      // per-quarter trip count (exec mask)
        const vi4 q0 = __builtin_nontemporal_load(reinterpret_cast<const vi4*>(ep + j));
        const vi4 q1 = __builtin_nontemporal_load(reinterpret_cast<const vi4*>(ep + j + 4));
        const vi2 r0 = *reinterpret_cast<const vi2*>(hb + (size_t)q0.x * 64);
        const vi2 r1 = *reinterpret_cast<const vi2*>(hb + (size_t)q0.y * 64);
        const vi2 r2 = *reinterpret_cast<const vi2*>(hb + (size_t)q0.z * 64);
        const vi2 r3 = *reinterpret_cast<const vi2*>(hb + (size_t)q0.w * 64);
        const vi2 r4 = *reinterpret_cast<const vi2*>(hb + (size_t)q1.x * 64);
        const vi2 r5 = *reinterpret_cast<const vi2*>(hb + (size_t)q1.y * 64);
        const vi2 r6 = *reinterpret_cast<const vi2*>(hb + (size_t)q1.z * 64);
        const vi2 r7 = *reinterpret_cast<const vi2*>(hb + (size_t)q1.w * 64);
        #define ACC(r) { \
            const float2 u = h2f(r.x); \
            const float2 w2 = h2f(r.y); \
            a0 += u.x; a1 += u.y; a2 += w2.x; a3 += w2.y; }
        ACC(r0) ACC(r1) ACC(r2) ACC(r3) ACC(r4) ACC(r5) ACC(r6) ACC(r7)
        #undef ACC
    }
    const float dv = dinv[v];
    const float4 bs = *reinterpret_cast<const float4*>(bias + l * 4);
    vf4 o;
    o.x = dv * a0 + bs.x; o.y = dv * a1 + bs.y;
    o.z = dv * a2 + bs.z; o.w = dv * a3 + bs.w;
    __builtin_nontemporal_store(o,
        reinterpret_cast<vf4*>(Hout + (size_t)v * 64 + l * 4));
}

// ---------------- FUSED prop(i) + gemm(i+1): ----------------
// Phase A: stage W hi/lo into LDS. Phase B: propagate 128 nodes (8 rounds of
// baseline gather structure), write fp16 rows DIRECTLY into the GEMM sA tile
// (identical rounding to the old h_c intermediate). Phase C: MFMA + epilogue.
// Removes the 25.6 MB h_c round-trip per fused layer.

__global__ __launch_bounds__(256) void k_fused(const __half* __restrict__ Hin,
                                               const int* __restrict__ csr,
                                               const int* __restrict__ offs,
                                               const int* __restrict__ deg_c,
                                               const float* __restrict__ dinv,
                                               const float* __restrict__ biasp,  // prop bias (layer i)
                                               const float* __restrict__ W,      // gemm weights (layer i+1)
                                               __half* __restrict__ H16) {
    constexpr int SA = 72;
    constexpr int SB = 72;
    __shared__ __align__(16) _Float16 sA[128 * SA];   // prop output rows (fp16)
    __shared__ __align__(16) _Float16 sBh[64 * SB];
    __shared__ __align__(16) _Float16 sBl[64 * SB];
    const int t = threadIdx.x;
    const int w = t >> 6, lane = t & 63;
    const int quad = lane >> 4, l16 = lane & 15;
    const int nb = blockIdx.x * 128;

    // phase A: stage W (64x64) hi/lo transposed [c][k]
    for (int i = t; i < 64 * 16; i += 256) {
        const int k = i >> 4, c4 = (i & 15) * 4;
        const float4 wv = *reinterpret_cast<const float4*>(W + (size_t)k * 64 + c4);
        const float wf[4] = {wv.x, wv.y, wv.z, wv.w};
        #pragma unroll
        for (int j = 0; j < 4; j++) {
            const _Float16 hi = (_Float16)wf[j];
            sBh[(c4 + j) * SB + k] = hi;
            sBl[(c4 + j) * SB + k] = (_Float16)(wf[j] - (float)hi);
        }
    }

    // phase B: propagation, 8 rounds x 16 nodes (wave quads), rows -> sA
    const float4 bs = *reinterpret_cast<const float4*>(biasp + l16 * 4);
    const __half* hb = Hin + l16 * 4;
    for (int r = 0; r < 8; r++) {
        const int ln = r * 16 + w * 4 + quad;     // local node 0..127
        const int v = nb + ln;
        float a0 = 0.f, a1 = 0.f, a2 = 0.f, a3 = 0.f;
        if (v < N_NODES) {
            const int start = offs[v];
            const int cp = (deg_c[v] + 7) & ~7;
            const int* ep = csr + start;
            for (int j = 0; j < cp; j += 8) {
                const vi4 q0 = __builtin_nontemporal_load(reinterpret_cast<const vi4*>(ep + j));
                const vi4 q1 = __builtin_nontemporal_load(reinterpret_cast<const vi4*>(ep + j + 4));
                const vi2 r0 = *reinterpret_cast<const vi2*>(hb + (size_t)q0.x * 64);
                const vi2 r1 = *reinterpret_cast<const vi2*>(hb + (size_t)q0.y * 64);
                const vi2 r2 = *reinterpret_cast<const vi2*>(hb + (size_t)q0.z * 64);
                const vi2 r3 = *reinterpret_cast<const vi2*>(hb + (size_t)q0.w * 64);
                const vi2 r4 = *reinterpret_cast<const vi2*>(hb + (size_t)q1.x * 64);
                const vi2 r5 = *reinterpret_cast<const vi2*>(hb + (size_t)q1.y * 64);
                const vi2 r6 = *reinterpret_cast<const vi2*>(hb + (size_t)q1.z * 64);
                const vi2 r7 = *reinterpret_cast<const vi2*>(hb + (size_t)q1.w * 64);
                #define ACC(rr) { \
                    const float2 u = h2f(rr.x); \
                    const float2 w2 = h2f(rr.y); \
                    a0 += u.x; a1 += u.y; a2 += w2.x; a3 += w2.y; }
                ACC(r0) ACC(r1) ACC(r2) ACC(r3) ACC(r4) ACC(r5) ACC(r6) ACC(r7)
                #undef ACC
            }
            const float dv = dinv[v];
            a0 = dv * a0 + bs.x; a1 = dv * a1 + bs.y;
            a2 = dv * a2 + bs.z; a3 = dv * a3 + bs.w;
        }
        vi2 pk;
        pk.x = __builtin_bit_cast(int, __floats2half2_rn(a0, a1));
        pk.y = __builtin_bit_cast(int, __floats2half2_rn(a2, a3));
        *reinterpret_cast<vi2*>(&sA[ln * SA + l16 * 4]) = pk;   // 8B LDS store
    }
    __syncthreads();

    // phase C: MFMA (CIN=64, single chunk) + epilogue
    v4f acc[2][4] = {};
    #pragma unroll
    for (int kt = 0; kt < 2; kt++) {
        const int kb = kt * 32 + quad * 8;
        v8h afr[2], bh[4], bl[4];
        #pragma unroll
        for (int mt = 0; mt < 2; mt++)
            afr[mt] = *reinterpret_cast<const v8h*>(&sA[(w * 32 + mt * 16 + l16) * SA + kb]);
        #pragma unroll
        for (int nt = 0; nt < 4; nt++) {
            bh[nt] = *reinterpret_cast<const v8h*>(&sBh[(nt * 16 + l16) * SB + kb]);
            bl[nt] = *reinterpret_cast<const v8h*>(&sBl[(nt * 16 + l16) * SB + kb]);
        }
        #pragma unroll
        for (int mt = 0; mt < 2; mt++)
            #pragma unroll
            for (int nt = 0; nt < 4; nt++) {
                acc[mt][nt] = __builtin_amdgcn_mfma_f32_16x16x32_f16(afr[mt], bh[nt], acc[mt][nt], 0, 0, 0);
                acc[mt][nt] = __builtin_amdgcn_mfma_f32_16x16x32_f16(afr[mt], bl[nt], acc[mt][nt], 0, 0, 0);
            }
    }
    #pragma unroll
    for (int mt = 0; mt < 2; mt++) {
        #pragma unroll
        for (int reg = 0; reg < 4; reg++) {
            const int node = nb + w * 32 + mt * 16 + quad * 4 + reg;
            if (node < N_NODES) {
                const float dv = dinv[node];
                #pragma unroll
                for (int nt = 0; nt < 4; nt++)
                    H16[(size_t)node * 64 + nt * 16 + l16] =
                        __float2half(acc[mt][nt][reg] * dv);
            }
        }
    }
}

// ---------------- pooling: one (graph, split) block; atomic-free partials ----------------

__global__ __launch_bounds__(256) void k_pool(const float* __restrict__ H,
                                              const int* __restrict__ batch,
                                              float* __restrict__ partial) {
    const int g = blockIdx.x >> 2;           // graph
    const int s = blockIdx.x & (SPLIT - 1);  // split
    int lo = 0, hi = N_NODES;
    while (lo < hi) { int m = (lo + hi) >> 1; if (batch[m] < g) lo = m + 1; else hi = m; }
    const int a = lo;
    lo = 0; hi = N_NODES;
    while (lo < hi) { int m = (lo + hi) >> 1; if (batch[m] < g + 1) lo = m + 1; else hi = m; }
    const int b = lo;

    const int wave = threadIdx.x >> 6, lane = threadIdx.x & 63;
    const int lane16 = s * 4 + wave;         // 0..15: stride position
    float ac0 = 0.f, ac1 = 0.f, ac2 = 0.f, ac3 = 0.f;
    int v = a + lane16;
    for (; v + 48 < b; v += 64) {            // 4 independent loads in flight
        ac0 += H[(size_t)v * 64 + lane];
        ac1 += H[(size_t)(v + 16) * 64 + lane];
        ac2 += H[(size_t)(v + 32) * 64 + lane];
        ac3 += H[(size_t)(v + 48) * 64 + lane];
    }
    for (; v < b; v += 16) ac0 += H[(size_t)v * 64 + lane];
    const float acc = (ac0 + ac1) + (ac2 + ac3);

    __shared__ float red[4][64];
    red[wave][lane] = acc;
    __syncthreads();
    if (wave == 0) {
        const float r = (red[0][lane] + red[1][lane]) + (red[2][lane] + red[3][lane]);
        partial[((size_t)s * N_GRAPHS + g) * 64 + lane] = r;
    }
}

__global__ void k_final(const float* __restrict__ partial, const int* __restrict__ batch,
                        const float* __restrict__ Wl, const float* __restrict__ bl,
                        float* __restrict__ out) {
    __shared__ int scnt[128];
    int t = threadIdx.x;
    int lo = 0, hi = N_NODES;
    while (lo < hi) { int mid = (lo + hi) >> 1; if (batch[mid] < t) lo = mid + 1; else hi = mid; }
    int a = lo;
    lo = 0; hi = N_NODES;
    while (lo < hi) { int mid = (lo + hi) >> 1; if (batch[mid] < t + 1) lo = mid + 1; else hi = mid; }
    scnt[t] = lo - a;
    __syncthreads();
    for (int off = 64; off > 0; off >>= 1) {
        if (t < off) scnt[t] = max(scnt[t], scnt[t + off]);
        __syncthreads();
    }
    const float nmax = (float)scnt[0];
    float s = 0.f;
    for (int c = 0; c < 64; c++) {
        float g = 0.f;
        #pragma unroll
        for (int p = 0; p < SPLIT; p++)
            g += partial[((size_t)p * N_GRAPHS + t) * 64 + c];
        s += g * Wl[c];
    }
    out[t] = s / nmax + bl[0];
}

// ---------------- launch ----------------

extern "C" void kernel_launch(void* const* d_in, const int* in_sizes, int n_in,
                              void* d_out, int out_size, void* d_ws, size_t ws_size,
                              hipStream_t stream) {
    const float* x    = (const float*)d_in[0];
    const int*   ei   = (const int*)d_in[1];     // [2, E] int32
    const int*   batch= (const int*)d_in[2];
    const float* W1 = (const float*)d_in[3];  const float* b1 = (const float*)d_in[4];
    const float* W2 = (const float*)d_in[5];  const float* b2 = (const float*)d_in[6];
    const float* W3 = (const float*)d_in[7];  const float* b3 = (const float*)d_in[8];
    const float* W4 = (const float*)d_in[9];  const float* b4 = (const float*)d_in[10];
    const float* Wl = (const float*)d_in[11]; const float* bl = (const float*)d_in[12];
    float* out = (float*)d_out;

    const int* row = ei;
    const int* col = ei + N_EDGES;

    // workspace layout (256B aligned blocks)
    char* ws = (char*)d_ws;
    size_t off = 0;
    auto alloc = [&](size_t bytes) {
        void* p = ws + off;
        off = (off + bytes + 255) & ~(size_t)255;
        return p;
    };
    int*    hist_t  = (int*)alloc((size_t)NB * BLK * 4);
    int*    cursors = (int*)alloc((size_t)NB * BLK * 4);
    int*    bcnt    = (int*)alloc(NB * 4);
    int*    bedges  = (int*)alloc((size_t)NB * CAP * 4);   // aliased by csr
    int*    csr     = bedges;                              // in-place rebuild (safe)
    int*    offs    = (int*)alloc(N_NODES * 4);
    int*    deg_c   = (int*)alloc(N_NODES * 4);
    float*  dinv    = (float*)alloc(N_NODES * 4);
    __half* h16a    = (__half*)alloc((size_t)(N_NODES + 1) * 64 * 2);  // gather table A (+1 zero row)
    __half* h16b    = (__half*)alloc((size_t)(N_NODES + 1) * 64 * 2);  // gather table B (+1 zero row)
    float*  h_b     = (float*)alloc((size_t)N_NODES * 64 * 4);         // fp32 prop output (layer 4)
    float*  partial = (float*)alloc((size_t)SPLIT * N_GRAPHS * 64 * 4);

    // zero sentinel rows (row N_NODES, 128 B each)
    (void)hipMemsetAsync(h16a + (size_t)N_NODES * 64, 0, 64 * 2, stream);
    (void)hipMemsetAsync(h16b + (size_t)N_NODES * 64, 0, 64 * 2, stream);

    // CSR build: histogram -> cursors -> bucket scatter -> per-bucket build
    k_hist<<<BLK, 256, 0, stream>>>(col, hist_t);
    k_cursors<<<NB, 512, 0, stream>>>(hist_t, cursors, bcnt);
    k_mid<<<BLK, 256, 0, stream>>>(row, col, cursors, bedges);
    k_build<<<NB, 512, 0, stream>>>(bedges, bcnt, csr, offs, deg_c, dinv);

    const int GB = (N_NODES + 127) / 128;   // 782 blocks (gemm1 / fused)
    const int PB = N_NODES / 16;            // 6250 prop blocks (16 nodes/block)

    // layer 1 gemm: h16a = fp16(dinv * (x @ W1))
    k_gemm<128><<<GB, 256, 0, stream>>>(x, W1, dinv, h16a);
    // fused: prop1(b1) + gemm2 -> h16b
    k_fused<<<GB, 256, 0, stream>>>(h16a, csr, offs, deg_c, dinv, b1, W2, h16b);
    // fused: prop2(b2) + gemm3 -> h16a
    k_fused<<<GB, 256, 0, stream>>>(h16b, csr, offs, deg_c, dinv, b2, W3, h16a);
    // fused: prop3(b3) + gemm4 -> h16b
    k_fused<<<GB, 256, 0, stream>>>(h16a, csr, offs, deg_c, dinv, b3, W4, h16b);
    // layer 4 prop: fp32 output for pooling
    k_prop_f<<<PB, 256, 0, stream>>>(h16b, csr, offs, deg_c, dinv, b4, h_b);

    // pooling + readout (atomic-free)
    k_pool<<<N_GRAPHS * SPLIT, 256, 0, stream>>>(h_b, batch, partial);
    k_final<<<1, 128, 0, stream>>>(partial, batch, Wl, bl, out);
}

// Round 5
// 378.181 us; speedup vs baseline: 1.3324x; 1.0409x over previous
//
#include <hip/hip_runtime.h>
#include <hip/hip_bf16.h>
#include <hip/hip_fp16.h>

// Problem constants (match reference)
#define N_NODES 100000
#define N_EDGES 1600000
#define N_GRAPHS 128

// Counting-sort CSR build parameters (pad-8)
#define BSH 9                 // bucket = col >> 9
#define BNODES 512            // nodes per bucket
#define NB 196                // ceil(100000 / 512)
#define CAP 12288             // static per-bucket csr/record capacity (elems)
#define BLK 512               // histogram blocks
#define EPB (N_EDGES / BLK)   // 3125 edges per block (exact)
#define RECMAX 10240          // max records per bucket held in LDS

#define SPLIT 4               // pooling blocks per graph

typedef __attribute__((ext_vector_type(8))) _Float16 v8h;
typedef __attribute__((ext_vector_type(4))) float v4f;
typedef __attribute__((ext_vector_type(4))) int vi4;
typedef __attribute__((ext_vector_type(2))) int vi2;
typedef __attribute__((ext_vector_type(4))) float vf4;

// unpack 2 halves packed in an int -> float2 (value-level)
__device__ __forceinline__ float2 h2f(int bits) {
    return __half22float2(__builtin_bit_cast(__half2, bits));
}

__device__ __forceinline__ v8h zero8h() {
    v8h z = {(_Float16)0, (_Float16)0, (_Float16)0, (_Float16)0,
             (_Float16)0, (_Float16)0, (_Float16)0, (_Float16)0};
    return z;
}

// ---------------- CSR build (no global atomics) ----------------

__global__ __launch_bounds__(256) void k_hist(const int* __restrict__ col,
                                              int* __restrict__ hist_t) {
    __shared__ int h[NB];
    const int t = threadIdx.x, b = blockIdx.x;
    for (int i = t; i < NB; i += 256) h[i] = 0;
    __syncthreads();
    const int e0 = b * EPB;
    for (int i = t; i < EPB; i += 256) atomicAdd(&h[col[e0 + i] >> BSH], 1);
    __syncthreads();
    for (int i = t; i < NB; i += 256) hist_t[i * BLK + b] = h[i];
}

__global__ __launch_bounds__(512) void k_cursors(const int* __restrict__ hist_t,
                                                 int* __restrict__ cursors,
                                                 int* __restrict__ bcnt) {
    __shared__ int s[BLK];
    const int t = threadIdx.x, bin = blockIdx.x;
    const int v = hist_t[bin * BLK + t];
    s[t] = v; __syncthreads();
    for (int off = 1; off < BLK; off <<= 1) {
        int a = (t >= off) ? s[t - off] : 0;
        __syncthreads(); s[t] += a; __syncthreads();
    }
    cursors[bin * BLK + t] = bin * CAP + s[t] - v;   // exclusive + static base
    if (t == BLK - 1) bcnt[bin] = s[t];
}

__global__ __launch_bounds__(256) void k_mid(const int* __restrict__ row,
                                             const int* __restrict__ col,
                                             const int* __restrict__ cursors,
                                             int* __restrict__ bedges) {
    __shared__ int cur[NB];
    const int t = threadIdx.x, b = blockIdx.x;
    for (int i = t; i < NB; i += 256) cur[i] = cursors[i * BLK + b];
    __syncthreads();
    const int e0 = b * EPB;
    for (int i = t; i < EPB; i += 256) {
        const int c = col[e0 + i];
        const int r = row[e0 + i];
        const int pos = atomicAdd(&cur[c >> BSH], 1);
        bedges[pos] = r | ((c & (BNODES - 1)) << 17);   // row<2^17, lcol 9 bits
    }
}

__global__ __launch_bounds__(512) void k_build(const int* __restrict__ bedges,
                                               const int* __restrict__ bcnt,
                                               int* __restrict__ csr,
                                               int* __restrict__ offs,
                                               int* __restrict__ deg_c,
                                               float* __restrict__ dinv) {
    __shared__ int rec[RECMAX];
    __shared__ int deg[BNODES];
    __shared__ int offx[BNODES];
    __shared__ int cur[BNODES];
    const int t = threadIdx.x, bin = blockIdx.x;
    const int base = bin * CAP;
    const int cnt = bcnt[bin];
    const int vb = bin << BSH;
    const int nn = min(BNODES, N_NODES - vb);
    for (int i = t; i < cnt; i += 512) rec[i] = bedges[base + i];
    deg[t] = 0;
    __syncthreads();                 // all record loads done before any csr write
    for (int i = t; i < cnt; i += 512) atomicAdd(&deg[(rec[i] >> 17) & (BNODES - 1)], 1);
    __syncthreads();
    const int d = (t < nn) ? deg[t] : 0;
    const int pd = (d + 7) & ~7;     // pad each segment to x8 (8-deep gather unroll)
    offx[t] = pd; __syncthreads();
    for (int off = 1; off < BNODES; off <<= 1) {
        int a = (t >= off) ? offx[t - off] : 0;
        __syncthreads(); offx[t] += a; __syncthreads();
    }
    const int myoff = offx[t] - pd;  // exclusive
    cur[t] = myoff;
    if (t < nn) {
        offs[vb + t] = base + myoff;
        deg_c[vb + t] = d;
        dinv[vb + t] = (d > 0) ? rsqrtf((float)d) : 0.0f;
        for (int j = d; j < pd; j++) csr[base + myoff + j] = N_NODES;  // sentinel
    }
    __syncthreads();
    for (int i = t; i < cnt; i += 512) {
        const int r = rec[i];
        const int pos = atomicAdd(&cur[(r >> 17) & (BNODES - 1)], 1);
        csr[base + pos] = r & 0x1FFFF;
    }
}

// ---------------- MFMA GEMM: H16[n][64] = fp16(dinv[n] * (X[n,:] @ W)) ----------------
// 64-node x 64-ch tile, 4 waves (one 16-row mtile each). Only W lives in LDS
// (hi+lo fp16 split -> ~exact weights); A-fragments are loaded DIRECTLY from
// global (16 B/lane, L2/L3-warm) -> one barrier total, 18.4/34.8 KB LDS.

template <int CIN, typename TIN>
__global__ __launch_bounds__(256) void k_gemm(const TIN* __restrict__ X,
                                              const float* __restrict__ W,
                                              const float* __restrict__ dinv,
                                              __half* __restrict__ H16) {
    constexpr int SBK = CIN + 8;                 // padded k-extent (keeps 16B align: 144/272 B rows)
    __shared__ __align__(16) _Float16 sBh[64 * SBK];
    __shared__ __align__(16) _Float16 sBl[64 * SBK];
    const int t = threadIdx.x;
    const int w = t >> 6, lane = t & 63;
    const int quad = lane >> 4, l16 = lane & 15;
    const int nb = blockIdx.x * 64;

    // stage all W [CIN x 64] -> transposed hi/lo [c][k]
    for (int i = t; i < CIN * 16; i += 256) {
        const int k = i >> 4, c4 = (i & 15) * 4;
        const float4 wv = *reinterpret_cast<const float4*>(W + (size_t)k * 64 + c4);
        const float wf[4] = {wv.x, wv.y, wv.z, wv.w};
        #pragma unroll
        for (int j = 0; j < 4; j++) {
            const _Float16 hi = (_Float16)wf[j];
            sBh[(c4 + j) * SBK + k] = hi;
            sBl[(c4 + j) * SBK + k] = (_Float16)(wf[j] - (float)hi);
        }
    }
    __syncthreads();

    const int gn = nb + w * 16 + l16;            // A-fragment row for this lane
    v4f acc[4] = {};                             // [ntile]

    #pragma unroll
    for (int k0 = 0; k0 < CIN; k0 += 32) {
        const int kb = k0 + quad * 8;
        v8h afr;
        if (gn < N_NODES) {
            if constexpr (sizeof(TIN) == 2) {
                afr = *reinterpret_cast<const v8h*>((const __half*)X + (size_t)gn * CIN + kb);
            } else {
                const float4 u0 = *reinterpret_cast<const float4*>((const float*)X + (size_t)gn * CIN + kb);
                const float4 u1 = *reinterpret_cast<const float4*>((const float*)X + (size_t)gn * CIN + kb + 4);
                afr[0] = (_Float16)u0.x; afr[1] = (_Float16)u0.y;
                afr[2] = (_Float16)u0.z; afr[3] = (_Float16)u0.w;
                afr[4] = (_Float16)u1.x; afr[5] = (_Float16)u1.y;
                afr[6] = (_Float16)u1.z; afr[7] = (_Float16)u1.w;
            }
        } else {
            afr = zero8h();
        }
        v8h bh[4], bl[4];
        #pragma unroll
        for (int nt = 0; nt < 4; nt++) {
            bh[nt] = *reinterpret_cast<const v8h*>(&sBh[(nt * 16 + l16) * SBK + kb]);
            bl[nt] = *reinterpret_cast<const v8h*>(&sBl[(nt * 16 + l16) * SBK + kb]);
        }
        #pragma unroll
        for (int nt = 0; nt < 4; nt++) {
            acc[nt] = __builtin_amdgcn_mfma_f32_16x16x32_f16(afr, bh[nt], acc[nt], 0, 0, 0);
            acc[nt] = __builtin_amdgcn_mfma_f32_16x16x32_f16(afr, bl[nt], acc[nt], 0, 0, 0);
        }
    }

    // epilogue: D row = quad*4+reg, col = l16
    #pragma unroll
    for (int reg = 0; reg < 4; reg++) {
        const int node = nb + w * 16 + quad * 4 + reg;
        if (node < N_NODES) {
            const float dv = dinv[node];
            #pragma unroll
            for (int nt = 0; nt < 4; nt++)
                H16[(size_t)node * 64 + nt * 16 + l16] =
                    __float2half(acc[nt][reg] * dv);
        }
    }
}

// ---------------- propagation: Hout[v] = dinv[v] * sum_e fp32(H16[row_e]) + bias ------
// R0 structure: 4 nodes/wave (quads), lane owns 4 channels (8 B); each gather
// inst serves 4 full 128B rows (8 lanes per 64B line); 8-deep unroll; 16 VGPR,
// no LDS -> max occupancy. TOUT = __half (layers 1-3, plain store, stays in L2
// for the next gemm) or float (layer 4, NT store, feeds pooling).

template <typename TOUT>
__global__ __launch_bounds__(256) void k_prop(const __half* __restrict__ Hin,
                                              const int* __restrict__ csr,
                                              const int* __restrict__ offs,
                                              const int* __restrict__ deg_c,
                                              const float* __restrict__ dinv,
                                              const float* __restrict__ bias,
                                              TOUT* __restrict__ Hout) {
    const int wave = threadIdx.x >> 6, lane = threadIdx.x & 63;
    const int quad = lane >> 4;            // node slot within the wave
    const int l = lane & 15;               // channel group: channels 4l..4l+3
    const int v = blockIdx.x * 16 + wave * 4 + quad;   // grid exact: v < N_NODES
    const int start = offs[v];             // multiple of 8 -> 32B aligned
    const int cp = (deg_c[v] + 7) & ~7;
    const int* ep = csr + start;
    const __half* hb = Hin + l * 4;
    float a0 = 0.f, a1 = 0.f, a2 = 0.f, a3 = 0.f;
    for (int j = 0; j < cp; j += 8) {      // per-quarter trip count (exec mask)
        const vi4 q0 = __builtin_nontemporal_load(reinterpret_cast<const vi4*>(ep + j));
        const vi4 q1 = __builtin_nontemporal_load(reinterpret_cast<const vi4*>(ep + j + 4));
        const vi2 r0 = *reinterpret_cast<const vi2*>(hb + (size_t)q0.x * 64);
        const vi2 r1 = *reinterpret_cast<const vi2*>(hb + (size_t)q0.y * 64);
        const vi2 r2 = *reinterpret_cast<const vi2*>(hb + (size_t)q0.z * 64);
        const vi2 r3 = *reinterpret_cast<const vi2*>(hb + (size_t)q0.w * 64);
        const vi2 r4 = *reinterpret_cast<const vi2*>(hb + (size_t)q1.x * 64);
        const vi2 r5 = *reinterpret_cast<const vi2*>(hb + (size_t)q1.y * 64);
        const vi2 r6 = *reinterpret_cast<const vi2*>(hb + (size_t)q1.z * 64);
        const vi2 r7 = *reinterpret_cast<const vi2*>(hb + (size_t)q1.w * 64);
        #define ACC(r) { \
            const float2 u = h2f(r.x); \
            const float2 w2 = h2f(r.y); \
            a0 += u.x; a1 += u.y; a2 += w2.x; a3 += w2.y; }
        ACC(r0) ACC(r1) ACC(r2) ACC(r3) ACC(r4) ACC(r5) ACC(r6) ACC(r7)
        #undef ACC
    }
    const float dv = dinv[v];
    const float4 bs = *reinterpret_cast<const float4*>(bias + l * 4);
    const float o0 = dv * a0 + bs.x, o1 = dv * a1 + bs.y;
    const float o2 = dv * a2 + bs.z, o3 = dv * a3 + bs.w;
    if constexpr (sizeof(TOUT) == 2) {
        vi2 pk;
        pk.x = __builtin_bit_cast(int, __floats2half2_rn(o0, o1));
        pk.y = __builtin_bit_cast(int, __floats2half2_rn(o2, o3));
        *reinterpret_cast<vi2*>((__half*)Hout + (size_t)v * 64 + l * 4) = pk;
    } else {
        vf4 o; o.x = o0; o.y = o1; o.z = o2; o.w = o3;
        __builtin_nontemporal_store(o,
            reinterpret_cast<vf4*>((float*)Hout + (size_t)v * 64 + l * 4));
    }
}

// ---------------- pooling: one (graph, split) block; atomic-free partials ----------------

__global__ __launch_bounds__(256) void k_pool(const float* __restrict__ H,
                                              const int* __restrict__ batch,
                                              float* __restrict__ partial) {
    const int g = blockIdx.x >> 2;           // graph
    const int s = blockIdx.x & (SPLIT - 1);  // split
    int lo = 0, hi = N_NODES;
    while (lo < hi) { int m = (lo + hi) >> 1; if (batch[m] < g) lo = m + 1; else hi = m; }
    const int a = lo;
    lo = 0; hi = N_NODES;
    while (lo < hi) { int m = (lo + hi) >> 1; if (batch[m] < g + 1) lo = m + 1; else hi = m; }
    const int b = lo;

    const int wave = threadIdx.x >> 6, lane = threadIdx.x & 63;
    const int lane16 = s * 4 + wave;         // 0..15: stride position
    float ac0 = 0.f, ac1 = 0.f, ac2 = 0.f, ac3 = 0.f;
    int v = a + lane16;
    for (; v + 48 < b; v += 64) {            // 4 independent loads in flight
        ac0 += H[(size_t)v * 64 + lane];
        ac1 += H[(size_t)(v + 16) * 64 + lane];
        ac2 += H[(size_t)(v + 32) * 64 + lane];
        ac3 += H[(size_t)(v + 48) * 64 + lane];
    }
    for (; v < b; v += 16) ac0 += H[(size_t)v * 64 + lane];
    const float acc = (ac0 + ac1) + (ac2 + ac3);

    __shared__ float red[4][64];
    red[wave][lane] = acc;
    __syncthreads();
    if (wave == 0) {
        const float r = (red[0][lane] + red[1][lane]) + (red[2][lane] + red[3][lane]);
        partial[((size_t)s * N_GRAPHS + g) * 64 + lane] = r;
    }
}

__global__ void k_final(const float* __restrict__ partial, const int* __restrict__ batch,
                        const float* __restrict__ Wl, const float* __restrict__ bl,
                        float* __restrict__ out) {
    __shared__ int scnt[128];
    int t = threadIdx.x;
    int lo = 0, hi = N_NODES;
    while (lo < hi) { int mid = (lo + hi) >> 1; if (batch[mid] < t) lo = mid + 1; else hi = mid; }
    int a = lo;
    lo = 0; hi = N_NODES;
    while (lo < hi) { int mid = (lo + hi) >> 1; if (batch[mid] < t + 1) lo = mid + 1; else hi = mid; }
    scnt[t] = lo - a;
    __syncthreads();
    for (int off = 64; off > 0; off >>= 1) {
        if (t < off) scnt[t] = max(scnt[t], scnt[t + off]);
        __syncthreads();
    }
    const float nmax = (float)scnt[0];
    float s = 0.f;
    for (int c = 0; c < 64; c++) {
        float g = 0.f;
        #pragma unroll
        for (int p = 0; p < SPLIT; p++)
            g += partial[((size_t)p * N_GRAPHS + t) * 64 + c];
        s += g * Wl[c];
    }
    out[t] = s / nmax + bl[0];
}

// ---------------- launch ----------------

extern "C" void kernel_launch(void* const* d_in, const int* in_sizes, int n_in,
                              void* d_out, int out_size, void* d_ws, size_t ws_size,
                              hipStream_t stream) {
    const float* x    = (const float*)d_in[0];
    const int*   ei   = (const int*)d_in[1];     // [2, E] int32
    const int*   batch= (const int*)d_in[2];
    const float* W1 = (const float*)d_in[3];  const float* b1 = (const float*)d_in[4];
    const float* W2 = (const float*)d_in[5];  const float* b2 = (const float*)d_in[6];
    const float* W3 = (const float*)d_in[7];  const float* b3 = (const float*)d_in[8];
    const float* W4 = (const float*)d_in[9];  const float* b4 = (const float*)d_in[10];
    const float* Wl = (const float*)d_in[11]; const float* bl = (const float*)d_in[12];
    float* out = (float*)d_out;

    const int* row = ei;
    const int* col = ei + N_EDGES;

    // workspace layout (256B aligned blocks)
    char* ws = (char*)d_ws;
    size_t off = 0;
    auto alloc = [&](size_t bytes) {
        void* p = ws + off;
        off = (off + bytes + 255) & ~(size_t)255;
        return p;
    };
    int*    hist_t  = (int*)alloc((size_t)NB * BLK * 4);
    int*    cursors = (int*)alloc((size_t)NB * BLK * 4);
    int*    bcnt    = (int*)alloc(NB * 4);
    int*    bedges  = (int*)alloc((size_t)NB * CAP * 4);   // aliased by csr
    int*    csr     = bedges;                              // in-place rebuild (safe)
    int*    offs    = (int*)alloc(N_NODES * 4);
    int*    deg_c   = (int*)alloc(N_NODES * 4);
    float*  dinv    = (float*)alloc(N_NODES * 4);
    __half* h16     = (__half*)alloc((size_t)(N_NODES + 1) * 64 * 2);  // gather table (+1 zero row)
    __half* h_c     = (__half*)alloc((size_t)N_NODES * 64 * 2);        // fp16 prop output (layers 1-3)
    float*  h_b     = (float*)alloc((size_t)N_NODES * 64 * 4);         // fp32 prop output (layer 4)
    float*  partial = (float*)alloc((size_t)SPLIT * N_GRAPHS * 64 * 4);

    // zero sentinel row (row N_NODES, 128 B) — gemm never writes it
    (void)hipMemsetAsync(h16 + (size_t)N_NODES * 64, 0, 64 * 2, stream);

    // CSR build: histogram -> cursors -> bucket scatter -> per-bucket build
    k_hist<<<BLK, 256, 0, stream>>>(col, hist_t);
    k_cursors<<<NB, 512, 0, stream>>>(hist_t, cursors, bcnt);
    k_mid<<<BLK, 256, 0, stream>>>(row, col, cursors, bedges);
    k_build<<<NB, 512, 0, stream>>>(bedges, bcnt, csr, offs, deg_c, dinv);

    const int GB = (N_NODES + 63) / 64;     // 1563 gemm blocks (64-node tiles)
    const int PB = N_NODES / 16;            // 6250 prop blocks (16 nodes/block)

    // layer 1: h16 = fp16(dinv * (x @ W1)) ; h_c = fp16(dinv * prop(h16) + b1)
    k_gemm<128, float><<<GB, 256, 0, stream>>>(x, W1, dinv, h16);
    k_prop<__half><<<PB, 256, 0, stream>>>(h16, csr, offs, deg_c, dinv, b1, h_c);
    // layer 2
    k_gemm<64, __half><<<GB, 256, 0, stream>>>(h_c, W2, dinv, h16);
    k_prop<__half><<<PB, 256, 0, stream>>>(h16, csr, offs, deg_c, dinv, b2, h_c);
    // layer 3
    k_gemm<64, __half><<<GB, 256, 0, stream>>>(h_c, W3, dinv, h16);
    k_prop<__half><<<PB, 256, 0, stream>>>(h16, csr, offs, deg_c, dinv, b3, h_c);
    // layer 4: fp32 output for pooling
    k_gemm<64, __half><<<GB, 256, 0, stream>>>(h_c, W4, dinv, h16);
    k_prop<float><<<PB, 256, 0, stream>>>(h16, csr, offs, deg_c, dinv, b4, h_b);

    // pooling + readout (atomic-free)
    k_pool<<<N_GRAPHS * SPLIT, 256, 0, stream>>>(h_b, batch, partial);
    k_final<<<1, 128, 0, stream>>>(partial, batch, Wl, bl, out);
}